// Round 3
// baseline (850.161 us; speedup 1.0000x reference)
//
#include <hip/hip_runtime.h>

#define NEGF -1000000000.0f
#define LOG2E 1.4426950408889634f
#define LN2 0.6931471805599453f

constexpr int Bn = 64;
constexpr int Tn = 1000;
constexpr int Un = 250;

// gfx950-native base-2 transcendentals: v_exp_f32 is 2^x, v_log_f32 is log2(x)
__device__ __forceinline__ float exp2fast(float x) { return __builtin_amdgcn_exp2f(x); }
__device__ __forceinline__ float log2fast(float x) { return __builtin_amdgcn_logf(x); }
__device__ __forceinline__ float max3f(float a, float b, float c) { return fmaxf(fmaxf(a, b), c); }
__device__ __forceinline__ float min3f(float a, float b, float c) { return fminf(fminf(a, b), c); }
__device__ __forceinline__ float med3f(float a, float b, float c) { return __builtin_amdgcn_fmed3f(a, b, c); }

// ---------------------------------------------------------------------------
// Kernel 1: per-row log-softmax denominator, in log2 units.
// Z2[b*Tn+t] = log2( 2^(-1*LOG2E) + sum_{u<L} 2^(attn[b,t,u]*LOG2E) )
// One wave (64 lanes) per row; 4 waves per 256-thread block.
// ---------------------------------------------------------------------------
__global__ void __launch_bounds__(256) zrow_kernel(const float* __restrict__ attn,
                                                   const int* __restrict__ text_lens,
                                                   float* __restrict__ Z2) {
    int wid = threadIdx.x >> 6;
    int lane = threadIdx.x & 63;
    int row = blockIdx.x * 4 + wid;            // row = b*Tn + t
    if (row >= Bn * Tn) return;
    int b = row / Tn;
    int L = text_lens[b];
    const float* p = attn + (size_t)row * Un;

    float v[4];
    float m = (lane == 0) ? -LOG2E : NEGF;     // blank column (-1.0 nat)
#pragma unroll
    for (int i = 0; i < 4; ++i) {
        int u = lane + 64 * i;
        v[i] = (u < L) ? p[u] * LOG2E : NEGF;  // u < L <= 250 -> in bounds
        m = fmaxf(m, v[i]);
    }
#pragma unroll
    for (int off = 32; off; off >>= 1) m = fmaxf(m, __shfl_xor(m, off));
    // m is the global row max (>= -LOG2E) on all lanes now.
    float s = (lane == 0) ? exp2fast(-LOG2E - m) : 0.0f;
#pragma unroll
    for (int i = 0; i < 4; ++i) s += exp2fast(v[i] - m);  // NEGF-m -> underflow to 0
#pragma unroll
    for (int off = 32; off; off >>= 1) s += __shfl_xor(s, off);
    if (lane == 0) Z2[row] = m + log2fast(s);
}

// ---------------------------------------------------------------------------
// Kernel 2: CTC forward recursion. One wave (64 lanes) per batch element.
// State s = lane*8 + j, j in [0,8): 512 register-resident states (>= S=501).
// Runs on RAW logits (log2 units); softmax normalization applied at the end
// as  final = (fin_raw - sum_t Z2[t]) * LN2.
//
// Per-step structure is explicitly staged (all maxes/residuals from OLD
// values into fresh temps, then exps, then logs) so the 8 state-chains are
// visibly independent -> scheduler interleaves transcendental latency.
// lse uses the "max term == 2^0" identity: lse2 = 1 exp + 1 log,
// lse3 = 2 exp + 1 log via v_max3/v_med3/v_min3.
// ---------------------------------------------------------------------------
__global__ void __launch_bounds__(64) ctc_kernel(const float* __restrict__ attn,
                                                 const int* __restrict__ text_lens,
                                                 const int* __restrict__ mel_lens,
                                                 const float* __restrict__ Z2,
                                                 float* __restrict__ out) {
    int b = blockIdx.x;
    int lane = threadIdx.x;
    int L = text_lens[b];
    int n_t = mel_lens[b];
    const float* base = attn + (size_t)b * Tn * Un;

    float a0 = NEGF, a1 = NEGF, a2 = NEGF, a3 = NEGF;
    float a4 = NEGF, a5 = NEGF, a6 = NEGF, a7 = NEGF;
    if (lane == 0) a0 = 0.0f;

    auto load_row = [&](int t) -> float4 {
        // cols 4*lane .. 4*lane+3 of row t, pre-scaled to log2 units.
        // Row stride is 1000B -> 8B aligned float2 pairs.
        const float* p = base + t * Un + lane * 4;
        float4 r = make_float4(0.0f, 0.0f, 0.0f, 0.0f);
        if (lane < 62) {
            float2 lo = *(const float2*)p;
            float2 hi = *(const float2*)(p + 2);
            r = make_float4(lo.x * LOG2E, lo.y * LOG2E, hi.x * LOG2E, hi.y * LOG2E);
        } else if (lane == 62) {
            // cols 248,249 valid; 250,251 don't exist (never needed: col<=249)
            r.x = p[0] * LOG2E;
            r.y = p[1] * LOG2E;
        }
        return r;  // lane 63: states > 501, values irrelevant
    };

    float4 vn = load_row(0);
    for (int t = 0; t < n_t; ++t) {
        float4 v = vn;
        int t2 = (t + 1 < n_t) ? t + 1 : t;
        vn = load_row(t2);  // prefetch next row while computing this step

        float p7 = __shfl_up(a7, 1);   // alpha[8*lane - 1]
        if (lane == 0) p7 = NEGF;

        // --- stage 1: maxes + residuals from OLD alpha (8 independent chains)
        float M7 = max3f(a7, a6, a5), D7 = med3f(a7, a6, a5) - M7, E7 = min3f(a7, a6, a5) - M7;
        float M5 = max3f(a5, a4, a3), D5 = med3f(a5, a4, a3) - M5, E5 = min3f(a5, a4, a3) - M5;
        float M3 = max3f(a3, a2, a1), D3 = med3f(a3, a2, a1) - M3, E3 = min3f(a3, a2, a1) - M3;
        float M1 = max3f(a1, a0, p7), D1 = med3f(a1, a0, p7) - M1, E1 = min3f(a1, a0, p7) - M1;
        float M6 = fmaxf(a6, a5), N6 = fminf(a6, a5) - M6;
        float M4 = fmaxf(a4, a3), N4 = fminf(a4, a3) - M4;
        float M2 = fmaxf(a2, a1), N2 = fminf(a2, a1) - M2;
        float M0 = fmaxf(a0, p7), N0 = fminf(a0, p7) - M0;

        // --- stage 2: exps (12) -- max term contributes exactly 1.0
        float s7 = 1.0f + exp2fast(D7) + exp2fast(E7);
        float s5 = 1.0f + exp2fast(D5) + exp2fast(E5);
        float s3 = 1.0f + exp2fast(D3) + exp2fast(E3);
        float s1 = 1.0f + exp2fast(D1) + exp2fast(E1);
        float s6 = 1.0f + exp2fast(N6);
        float s4 = 1.0f + exp2fast(N4);
        float s2 = 1.0f + exp2fast(N2);
        float s0 = 1.0f + exp2fast(N0);

        // --- stage 3: logs (8) + emission adds
        a7 = M7 + log2fast(s7) + v.w;      // odd s: label col 4*lane+3
        a6 = M6 + log2fast(s6) - LOG2E;    // even s: blank (-1.0 nat)
        a5 = M5 + log2fast(s5) + v.z;
        a4 = M4 + log2fast(s4) - LOG2E;
        a3 = M3 + log2fast(s3) + v.y;
        a2 = M2 + log2fast(s2) - LOG2E;
        a1 = M1 + log2fast(s1) + v.x;
        a0 = M0 + log2fast(s0) - LOG2E;
    }

    __shared__ float sal[512];
    sal[lane * 8 + 0] = a0;
    sal[lane * 8 + 1] = a1;
    sal[lane * 8 + 2] = a2;
    sal[lane * 8 + 3] = a3;
    sal[lane * 8 + 4] = a4;
    sal[lane * 8 + 5] = a5;
    sal[lane * 8 + 6] = a6;
    sal[lane * 8 + 7] = a7;
    __syncthreads();

    // sum of log-softmax denominators over t < n_t (log2 units)
    float zs = 0.0f;
    for (int i = lane; i < n_t; i += 64) zs += Z2[b * Tn + i];
#pragma unroll
    for (int off = 32; off; off >>= 1) zs += __shfl_xor(zs, off);

    if (lane == 0) {
        float fA = sal[2 * L], fB = sal[2 * L - 1];
        float M = fmaxf(fA, fB);
        float fin2 = M + log2fast(1.0f + exp2fast(fminf(fA, fB) - M));
        float fin = (fin2 - zs) * LN2;           // back to natural log
        float loss = (fin < NEGF * 0.5f) ? 0.0f : (-fin / (float)L);
        atomicAdd(out, loss * (1.0f / (float)Bn));
    }
}

extern "C" void kernel_launch(void* const* d_in, const int* in_sizes, int n_in,
                              void* d_out, int out_size, void* d_ws, size_t ws_size,
                              hipStream_t stream) {
    const float* attn = (const float*)d_in[0];
    const int* text_lens = (const int*)d_in[1];
    const int* mel_lens = (const int*)d_in[2];
    float* out = (float*)d_out;
    float* Z2 = (float*)d_ws;  // Bn*Tn floats = 256 KB

    (void)hipMemsetAsync(d_out, 0, sizeof(float), stream);
    zrow_kernel<<<(Bn * Tn + 3) / 4, 256, 0, stream>>>(attn, text_lens, Z2);
    ctc_kernel<<<Bn, 64, 0, stream>>>(attn, text_lens, mel_lens, Z2, out);
}

// Round 4
// 826.030 us; speedup vs baseline: 1.0292x; 1.0292x over previous
//
#include <hip/hip_runtime.h>

#define NEGF -1000000000.0f
#define LOG2E 1.4426950408889634f
#define LN2 0.6931471805599453f

constexpr int Bn = 64;
constexpr int Tn = 1000;
constexpr int Un = 250;

// gfx950-native base-2 transcendentals: v_exp_f32 is 2^x, v_log_f32 is log2(x)
__device__ __forceinline__ float exp2fast(float x) { return __builtin_amdgcn_exp2f(x); }
__device__ __forceinline__ float log2fast(float x) { return __builtin_amdgcn_logf(x); }
__device__ __forceinline__ float max3f(float a, float b, float c) { return fmaxf(fmaxf(a, b), c); }
__device__ __forceinline__ float min3f(float a, float b, float c) { return fminf(fminf(a, b), c); }
__device__ __forceinline__ float med3f(float a, float b, float c) { return __builtin_amdgcn_fmed3f(a, b, c); }

// ---------------------------------------------------------------------------
// Kernel 1: per-row log-softmax denominator, in log2 units.
// Z2[b*Tn+t] = log2( 2^(-1*LOG2E) + sum_{u<L} 2^(attn[b,t,u]*LOG2E) )
// One wave (64 lanes) per row; 4 waves per 256-thread block.
// ---------------------------------------------------------------------------
__global__ void __launch_bounds__(256) zrow_kernel(const float* __restrict__ attn,
                                                   const int* __restrict__ text_lens,
                                                   float* __restrict__ Z2) {
    int wid = threadIdx.x >> 6;
    int lane = threadIdx.x & 63;
    int row = blockIdx.x * 4 + wid;            // row = b*Tn + t
    if (row >= Bn * Tn) return;
    int b = row / Tn;
    int L = text_lens[b];
    const float* p = attn + (size_t)row * Un;

    float v[4];
    float m = (lane == 0) ? -LOG2E : NEGF;     // blank column (-1.0 nat)
#pragma unroll
    for (int i = 0; i < 4; ++i) {
        int u = lane + 64 * i;
        v[i] = (u < L) ? p[u] * LOG2E : NEGF;  // u < L <= 250 -> in bounds
        m = fmaxf(m, v[i]);
    }
#pragma unroll
    for (int off = 32; off; off >>= 1) m = fmaxf(m, __shfl_xor(m, off));
    // m is the global row max (>= -LOG2E) on all lanes now.
    float s = (lane == 0) ? exp2fast(-LOG2E - m) : 0.0f;
#pragma unroll
    for (int i = 0; i < 4; ++i) s += exp2fast(v[i] - m);  // NEGF-m -> underflow to 0
#pragma unroll
    for (int off = 32; off; off >>= 1) s += __shfl_xor(s, off);
    if (lane == 0) Z2[row] = m + log2fast(s);
}

// ---------------------------------------------------------------------------
// lse in base-2 domain; max term contributes exactly 2^0 = 1.0:
//   lse2 = 1 exp + 1 log, lse3 = 2 exp + 1 log (v_max3/v_med3/v_min3)
// ---------------------------------------------------------------------------
__device__ __forceinline__ float lse2_2(float a, float b) {
    float m = fmaxf(a, b);
    return m + log2fast(1.0f + exp2fast(fminf(a, b) - m));
}
__device__ __forceinline__ float lse3_2(float a, float b, float c) {
    float m = max3f(a, b, c);
    return m + log2fast(1.0f + exp2fast(med3f(a, b, c) - m) + exp2fast(min3f(a, b, c) - m));
}

// ---------------------------------------------------------------------------
// Kernel 2: CTC forward recursion. One wave (64 lanes) per batch element.
// State s = lane*8 + j, j in [0,8): 512 register-resident states (>= S=501).
// Raw logits (log2 units); softmax normalization applied once at the end:
//   final = (fin_raw - sum_t Z2[t]) * LN2.
//
// The serial t-loop is latency-bound on the global row load with only 1
// wave/SIMD resident -> 4-deep register prefetch pipeline (unroll-by-4,
// 4 independent float4 buffers = 4 outstanding vmcnt loads) hides ~900-cycle
// HBM latency behind ~4 steps of compute. __launch_bounds__(64,1) gives the
// compiler the full VGPR budget so it doesn't pressure-serialize.
// In-place DESCENDING update (a7 first): new[j] = f(old[j], old[j-1],
// old[j-2]); shfl_up issued at the top, consumed last (a1/a0) -> its LDS
// latency overlaps the 6 intermediate lse chains.
// ---------------------------------------------------------------------------
__global__ void __launch_bounds__(64, 1) ctc_kernel(const float* __restrict__ attn,
                                                    const int* __restrict__ text_lens,
                                                    const int* __restrict__ mel_lens,
                                                    const float* __restrict__ Z2,
                                                    float* __restrict__ out) {
    int b = blockIdx.x;
    int lane = threadIdx.x;
    int L = text_lens[b];
    int n_t = mel_lens[b];
    const float* base = attn + (size_t)b * Tn * Un;

    float a0 = NEGF, a1 = NEGF, a2 = NEGF, a3 = NEGF;
    float a4 = NEGF, a5 = NEGF, a6 = NEGF, a7 = NEGF;
    if (lane == 0) a0 = 0.0f;

    auto load_row = [&](int t) -> float4 {
        // cols 4*lane .. 4*lane+3 of row t, pre-scaled to log2 units.
        // Row stride is 1000B -> float2 pairs always 8B aligned.
        const float* p = base + t * Un + lane * 4;
        float4 r = make_float4(0.0f, 0.0f, 0.0f, 0.0f);
        if (lane < 62) {
            float2 lo = *(const float2*)p;
            float2 hi = *(const float2*)(p + 2);
            r = make_float4(lo.x * LOG2E, lo.y * LOG2E, hi.x * LOG2E, hi.y * LOG2E);
        } else if (lane == 62) {
            // cols 248,249 valid; 250,251 don't exist (never needed: col<=249)
            r.x = p[0] * LOG2E;
            r.y = p[1] * LOG2E;
        }
        return r;  // lane 63: states > 501, values irrelevant
    };

    auto step = [&](const float4& v) {
        float p7 = __shfl_up(a7, 1);   // alpha[8*lane - 1]; consumed last
        if (lane == 0) p7 = NEGF;
        a7 = lse3_2(a7, a6, a5) + v.w;      // odd s: label col 4*lane+3
        a6 = lse2_2(a6, a5) - LOG2E;        // even s: blank (-1.0 nat)
        a5 = lse3_2(a5, a4, a3) + v.z;
        a4 = lse2_2(a4, a3) - LOG2E;
        a3 = lse3_2(a3, a2, a1) + v.y;
        a2 = lse2_2(a2, a1) - LOG2E;
        a1 = lse3_2(a1, a0, p7) + v.x;
        a0 = lse2_2(a0, p7) - LOG2E;
    };

    // ---- 4-deep prefetch pipeline ----
    int last = n_t - 1;
    float4 pf0 = load_row(0);
    float4 pf1 = load_row(min(1, last));
    float4 pf2 = load_row(min(2, last));
    float4 pf3 = load_row(min(3, last));

    int t = 0;
    for (; t + 4 <= n_t; t += 4) {
        step(pf0); pf0 = load_row(min(t + 4, last));
        step(pf1); pf1 = load_row(min(t + 5, last));
        step(pf2); pf2 = load_row(min(t + 6, last));
        step(pf3); pf3 = load_row(min(t + 7, last));
    }
    if (t + 0 < n_t) step(pf0);
    if (t + 1 < n_t) step(pf1);
    if (t + 2 < n_t) step(pf2);

    __shared__ float sal[512];
    sal[lane * 8 + 0] = a0;
    sal[lane * 8 + 1] = a1;
    sal[lane * 8 + 2] = a2;
    sal[lane * 8 + 3] = a3;
    sal[lane * 8 + 4] = a4;
    sal[lane * 8 + 5] = a5;
    sal[lane * 8 + 6] = a6;
    sal[lane * 8 + 7] = a7;
    __syncthreads();

    // sum of log-softmax denominators over t < n_t (log2 units)
    float zs = 0.0f;
    for (int i = lane; i < n_t; i += 64) zs += Z2[b * Tn + i];
#pragma unroll
    for (int off = 32; off; off >>= 1) zs += __shfl_xor(zs, off);

    if (lane == 0) {
        float fin2 = lse2_2(sal[2 * L], sal[2 * L - 1]);
        float fin = (fin2 - zs) * LN2;           // back to natural log
        float loss = (fin < NEGF * 0.5f) ? 0.0f : (-fin / (float)L);
        atomicAdd(out, loss * (1.0f / (float)Bn));
    }
}

extern "C" void kernel_launch(void* const* d_in, const int* in_sizes, int n_in,
                              void* d_out, int out_size, void* d_ws, size_t ws_size,
                              hipStream_t stream) {
    const float* attn = (const float*)d_in[0];
    const int* text_lens = (const int*)d_in[1];
    const int* mel_lens = (const int*)d_in[2];
    float* out = (float*)d_out;
    float* Z2 = (float*)d_ws;  // Bn*Tn floats = 256 KB

    (void)hipMemsetAsync(d_out, 0, sizeof(float), stream);
    zrow_kernel<<<(Bn * Tn + 3) / 4, 256, 0, stream>>>(attn, text_lens, Z2);
    ctc_kernel<<<Bn, 64, 0, stream>>>(attn, text_lens, mel_lens, Z2, out);
}

// Round 5
// 258.571 us; speedup vs baseline: 3.2879x; 3.1946x over previous
//
#include <hip/hip_runtime.h>

#define NEGF -1000000000.0f
#define LOG2E 1.4426950408889634f
#define LN2 0.6931471805599453f

constexpr int Bn = 64;
constexpr int Tn = 1000;
constexpr int Un = 250;

// gfx950-native base-2 transcendentals: v_exp_f32 is 2^x, v_log_f32 is log2(x)
__device__ __forceinline__ float exp2fast(float x) { return __builtin_amdgcn_exp2f(x); }
__device__ __forceinline__ float log2fast(float x) { return __builtin_amdgcn_logf(x); }

// ---------------------------------------------------------------------------
// Kernel 1: per-row log-softmax denominator, in log2 units.
// Z2[b*Tn+t] = log2( 2^(-1*LOG2E) + sum_{u<L} 2^(attn[b,t,u]*LOG2E) )
// One wave (64 lanes) per row; 4 waves per 256-thread block.  (unchanged,
// verified rounds 2-4)
// ---------------------------------------------------------------------------
__global__ void __launch_bounds__(256) zrow_kernel(const float* __restrict__ attn,
                                                   const int* __restrict__ text_lens,
                                                   float* __restrict__ Z2) {
    int wid = threadIdx.x >> 6;
    int lane = threadIdx.x & 63;
    int row = blockIdx.x * 4 + wid;            // row = b*Tn + t
    if (row >= Bn * Tn) return;
    int b = row / Tn;
    int L = text_lens[b];
    const float* p = attn + (size_t)row * Un;

    float v[4];
    float m = (lane == 0) ? -LOG2E : NEGF;     // blank column (-1.0 nat)
#pragma unroll
    for (int i = 0; i < 4; ++i) {
        int u = lane + 64 * i;
        v[i] = (u < L) ? p[u] * LOG2E : NEGF;  // u < L <= 250 -> in bounds
        m = fmaxf(m, v[i]);
    }
#pragma unroll
    for (int off = 32; off; off >>= 1) m = fmaxf(m, __shfl_xor(m, off));
    float s = (lane == 0) ? exp2fast(-LOG2E - m) : 0.0f;
#pragma unroll
    for (int i = 0; i < 4; ++i) s += exp2fast(v[i] - m);  // NEGF-m underflows to 0
#pragma unroll
    for (int off = 32; off; off >>= 1) s += __shfl_xor(s, off);
    if (lane == 0) Z2[row] = m + log2fast(s);
}

// ---------------------------------------------------------------------------
// Kernel 2: CTC forward recursion in the LINEAR domain, one wave per batch.
// State s = lane*8 + j; alpha kept as fp32 scaled by 2^-Esum (wave-uniform
// power-of-2 renorm every 8 steps via exponent-bit extraction).
//   odd  s: a' = (a[s]+a[s-1]+a[s-2]) * e^{logit[col]}   (col = (s+1)/2 - 1)
//   even s: a' = (a[s]+a[s-1]) * e^{-1}
// q masked to 0 for cols >= L  -> garbage states (s > 2L) stay exactly 0 and
// never pollute the renorm max. Softmax normalization folded in at the end:
//   final = (log2(a[2L]+a[2L-1]) + Esum - sum_t Z2[t]) * LN2.
//
// Loads: compiler provably sinks C-level prefetch (rounds 3/4) -> inline-asm
// global_load_dwordx2, 8-row rotation, manual s_waitcnt vmcnt(14) (16 loads
// in flight, wait for the oldest pair). Per-lane in-row byte offsets are
// remapped for lanes 62/63 so no load ever crosses a row end (no OOB, no
// divergence): lane62 hi aliases its lo (cols 248,249; its cols 250,251 are
// always masked since L<=250), lane63 reads col 0 (all its states masked).
// ---------------------------------------------------------------------------
typedef float v2f __attribute__((ext_vector_type(2)));

__global__ void __launch_bounds__(64, 1) ctc_kernel(const float* __restrict__ attn,
                                                    const int* __restrict__ text_lens,
                                                    const int* __restrict__ mel_lens,
                                                    const float* __restrict__ Z2,
                                                    float* __restrict__ out) {
    int b = blockIdx.x;
    int lane = threadIdx.x;
    int L = text_lens[b];
    int n_t = mel_lens[b];
    const char* pbase = (const char*)(attn + (size_t)b * Tn * Un);

    // per-lane safe byte offsets within a 1000B row (8B aligned)
    int lo_off = lane * 16, hi_off = lane * 16 + 8;
    if (lane == 62) { lo_off = 992; hi_off = 992; }
    if (lane == 63) { lo_off = 0;   hi_off = 0;   }
    int c0 = lane * 4;
    bool m0 = (c0 + 0) < L, m1 = (c0 + 1) < L;
    bool m2 = (c0 + 2) < L, m3 = (c0 + 3) < L;

    const float QB = 0.36787944117144233f;  // e^-1 (blank prob, unnormalized)
    float a0 = (lane == 0) ? 1.0f : 0.0f;
    float a1 = 0.0f, a2 = 0.0f, a3 = 0.0f, a4 = 0.0f, a5 = 0.0f, a6 = 0.0f, a7 = 0.0f;
    float Esum = 0.0f;  // accumulated renorm exponent, log2 units

    v2f lo[8], hi[8];
    int last = n_t - 1;

    // prologue: 8 rows = 16 loads in flight
#pragma unroll
    for (int j = 0; j < 8; ++j) {
        int tl = (j <= last) ? j : last;
        const char* pl = pbase + tl * 1000 + lo_off;
        const char* ph = pbase + tl * 1000 + hi_off;
        asm volatile("global_load_dwordx2 %0, %1, off" : "=v"(lo[j]) : "v"(pl));
        asm volatile("global_load_dwordx2 %0, %1, off" : "=v"(hi[j]) : "v"(ph));
    }

    int ngroups = (n_t + 7) >> 3;
    int t = 0;
    for (int g = 0; g < ngroups; ++g) {
#pragma unroll
        for (int j = 0; j < 8; ++j) {
            if (t + j < n_t) {  // wave-uniform guard (tail group)
                // wait for the 2 oldest of 16 outstanding loads (this slot)
                asm volatile("s_waitcnt vmcnt(14)" : "+v"(lo[j]), "+v"(hi[j]));
                float q0 = m0 ? exp2fast(lo[j].x * LOG2E) : 0.0f;
                float q1 = m1 ? exp2fast(lo[j].y * LOG2E) : 0.0f;
                float q2 = m2 ? exp2fast(hi[j].x * LOG2E) : 0.0f;
                float q3 = m3 ? exp2fast(hi[j].y * LOG2E) : 0.0f;

                float p7 = __shfl_up(a7, 1);  // alpha[8*lane - 1]
                if (lane == 0) p7 = 0.0f;

                float s65 = a6 + a5, s43 = a4 + a3, s21 = a2 + a1, s0p = a0 + p7;
                a7 = (a7 + s65) * q3;  a6 = s65 * QB;
                a5 = (a5 + s43) * q2;  a4 = s43 * QB;
                a3 = (a3 + s21) * q1;  a2 = s21 * QB;
                a1 = (a1 + s0p) * q0;  a0 = s0p * QB;

                // refill this slot with row t+j+8 (clamped; redundant re-reads
                // of the last row keep the vmcnt invariant exact)
                int tl = t + j + 8; tl = (tl <= last) ? tl : last;
                const char* pl = pbase + tl * 1000 + lo_off;
                const char* ph = pbase + tl * 1000 + hi_off;
                asm volatile("global_load_dwordx2 %0, %1, off" : "=v"(lo[j]) : "v"(pl));
                asm volatile("global_load_dwordx2 %0, %1, off" : "=v"(hi[j]) : "v"(ph));
            }
        }
        t += 8;

        // wave-uniform power-of-2 renorm (no transcendentals)
        float mx = fmaxf(fmaxf(fmaxf(a0, a1), fmaxf(a2, a3)),
                         fmaxf(fmaxf(a4, a5), fmaxf(a6, a7)));
#pragma unroll
        for (int off = 32; off; off >>= 1) mx = fmaxf(mx, __shfl_xor(mx, off));
        int e = (int)((__float_as_uint(mx) >> 23) & 255) - 127;
        float scale = __uint_as_float((unsigned)(127 - e) << 23);  // 2^-e
        a0 *= scale; a1 *= scale; a2 *= scale; a3 *= scale;
        a4 *= scale; a5 *= scale; a6 *= scale; a7 *= scale;
        Esum += (float)e;
    }
    asm volatile("s_waitcnt vmcnt(0)");  // drain stale prefetches

    __shared__ float sal[512];
    sal[lane * 8 + 0] = a0;
    sal[lane * 8 + 1] = a1;
    sal[lane * 8 + 2] = a2;
    sal[lane * 8 + 3] = a3;
    sal[lane * 8 + 4] = a4;
    sal[lane * 8 + 5] = a5;
    sal[lane * 8 + 6] = a6;
    sal[lane * 8 + 7] = a7;
    __syncthreads();

    // sum of log-softmax denominators over t < n_t (log2 units)
    float zs = 0.0f;
    for (int i = lane; i < n_t; i += 64) zs += Z2[b * Tn + i];
#pragma unroll
    for (int off = 32; off; off >>= 1) zs += __shfl_xor(zs, off);

    if (lane == 0) {
        float ssum = sal[2 * L] + sal[2 * L - 1];
        float fin = (log2fast(ssum) + Esum - zs) * LN2;
        float loss = (ssum <= 0.0f) ? 0.0f : (-fin / (float)L);
        atomicAdd(out, loss * (1.0f / (float)Bn));
    }
}

extern "C" void kernel_launch(void* const* d_in, const int* in_sizes, int n_in,
                              void* d_out, int out_size, void* d_ws, size_t ws_size,
                              hipStream_t stream) {
    const float* attn = (const float*)d_in[0];
    const int* text_lens = (const int*)d_in[1];
    const int* mel_lens = (const int*)d_in[2];
    float* out = (float*)d_out;
    float* Z2 = (float*)d_ws;  // Bn*Tn floats = 256 KB

    (void)hipMemsetAsync(d_out, 0, sizeof(float), stream);
    zrow_kernel<<<(Bn * Tn + 3) / 4, 256, 0, stream>>>(attn, text_lens, Z2);
    ctc_kernel<<<Bn, 64, 0, stream>>>(attn, text_lens, mel_lens, Z2, out);
}

// Round 6
// 194.086 us; speedup vs baseline: 4.3803x; 1.3323x over previous
//
#include <hip/hip_runtime.h>

#define NEGF -1000000000.0f
#define LOG2E 1.4426950408889634f
#define LN2 0.6931471805599453f

constexpr int Bn = 64;
constexpr int Tn = 1000;
constexpr int Un = 250;

// gfx950-native base-2 transcendentals: v_exp_f32 is 2^x, v_log_f32 is log2(x)
__device__ __forceinline__ float exp2fast(float x) { return __builtin_amdgcn_exp2f(x); }
__device__ __forceinline__ float log2fast(float x) { return __builtin_amdgcn_logf(x); }

// ---------------------------------------------------------------------------
// DPP cross-lane reductions: 6 dependent VALU stages (~60 cyc) instead of a
// 6-stage ds_swizzle butterfly (~720 cyc at ~120 cyc DS latency each).
// Valid when 0 is an identity for the op (add; max of non-negative values —
// bound_ctrl=1 inserts 0 for shifted-in lanes).
// row_shr:1/2/4/8 -> in-row prefix; row_bcast:15 (0x142) + row_bcast:31
// (0x143) combine the four 16-lane rows; lane 63 holds the result;
// v_readlane broadcasts it wave-uniformly (SGPR).
// ---------------------------------------------------------------------------
template <int CTRL>
__device__ __forceinline__ float dppmov(float x) {
    return __int_as_float(__builtin_amdgcn_update_dpp(
        0, __float_as_int(x), CTRL, 0xf, 0xf, true));
}
__device__ __forceinline__ float wave_red_max(float x) {  // x may be <0: result = max(max_x, 0)
    x = fmaxf(x, dppmov<0x111>(x));
    x = fmaxf(x, dppmov<0x112>(x));
    x = fmaxf(x, dppmov<0x114>(x));
    x = fmaxf(x, dppmov<0x118>(x));
    x = fmaxf(x, dppmov<0x142>(x));
    x = fmaxf(x, dppmov<0x143>(x));
    return __int_as_float(__builtin_amdgcn_readlane(__float_as_int(x), 63));
}
__device__ __forceinline__ float wave_red_sum(float x) {
    x += dppmov<0x111>(x);
    x += dppmov<0x112>(x);
    x += dppmov<0x114>(x);
    x += dppmov<0x118>(x);
    x += dppmov<0x142>(x);
    x += dppmov<0x143>(x);
    return __int_as_float(__builtin_amdgcn_readlane(__float_as_int(x), 63));
}

// ---------------------------------------------------------------------------
// Kernel 1: per-row log-softmax denominator, in log2 units.
// Z2[b*Tn+t] = log2( 2^(-1*LOG2E) + sum_{u<L} 2^(attn[b,t,u]*LOG2E) )
// One wave per row. Reductions via DPP; using m' = max(true_max, 0) is exact
// (the lse identity holds for any shift; logits are O(+-8) so no overflow).
// ---------------------------------------------------------------------------
__global__ void __launch_bounds__(256) zrow_kernel(const float* __restrict__ attn,
                                                   const int* __restrict__ text_lens,
                                                   float* __restrict__ Z2) {
    int wid = threadIdx.x >> 6;
    int lane = threadIdx.x & 63;
    int row = blockIdx.x * 4 + wid;            // row = b*Tn + t
    if (row >= Bn * Tn) return;
    int b = row / Tn;
    int L = text_lens[b];
    const float* p = attn + (size_t)row * Un;

    float v[4];
    float m = (lane == 0) ? -LOG2E : NEGF;     // blank column (-1.0 nat)
#pragma unroll
    for (int i = 0; i < 4; ++i) {
        int u = lane + 64 * i;
        v[i] = (u < L) ? p[u] * LOG2E : NEGF;  // u < L <= 250 -> in bounds
        m = fmaxf(m, v[i]);
    }
    m = wave_red_max(m);                       // wave-uniform, = max(max, 0)
    float s = (lane == 0) ? exp2fast(-LOG2E - m) : 0.0f;
#pragma unroll
    for (int i = 0; i < 4; ++i) s += exp2fast(v[i] - m);  // NEGF-m underflows to 0
    s = wave_red_sum(s);
    if (lane == 0) Z2[row] = m + log2fast(s);
}

// ---------------------------------------------------------------------------
// Kernel 2: CTC forward recursion in the LINEAR domain, one wave per batch.
// State s = lane*8 + j. Every 8 steps: wave-uniform power-of-2 renorm (DPP
// max + exponent bits), Esum accumulates the stripped exponent (log2 units).
//   odd  s: a' = (a[s]+a[s-1]+a[s-2]) * e^{logit[col]}
//   even s: a' = (a[s]+a[s-1]) * e^{-1}
// Column masking folded into the exp2 input as an fma bias (-1e6 -> q=0), so
// garbage states (s > 2L) stay exactly 0.
// Cross-lane alpha[8*lane-1]: shfl_up(na7) is issued right after na7 is
// produced and consumed NEXT step (p7c) -> ~120cyc ds_bpermute latency is
// covered by ~140cyc of independent work. p7c is rescaled at renorm.
// Loads: 16-row-deep rotation of inline-asm global_load_dwordx2 with SGPR row
// base + constant per-lane voffset (zero VALU addr math), s_waitcnt vmcnt(30)
// before consuming a slot. Branchless 16-step body; guarded 15-step tail.
// ---------------------------------------------------------------------------
typedef float v2f __attribute__((ext_vector_type(2)));

#define CTC_REFILL(J, T)                                                      \
    {                                                                         \
        int tl_ = (T) <= last ? (T) : last;                                   \
        const char* rowp_ = pbase + (size_t)tl_ * 1000;                       \
        asm volatile("global_load_dwordx2 %0, %1, %2"                         \
                     : "=v"(lo[J]) : "v"(voff_lo), "s"(rowp_));               \
        asm volatile("global_load_dwordx2 %0, %1, %2"                         \
                     : "=v"(hi[J]) : "v"(voff_hi), "s"(rowp_));               \
    }

#define CTC_STEP(J, WCNT)                                                     \
    {                                                                         \
        asm volatile("s_waitcnt vmcnt(" #WCNT ")"                             \
                     : "+v"(lo[J]), "+v"(hi[J]));                             \
        float q0 = exp2fast(__builtin_fmaf(lo[J].x, LOG2E, bias0));           \
        float q1 = exp2fast(__builtin_fmaf(lo[J].y, LOG2E, bias1));           \
        float q2 = exp2fast(__builtin_fmaf(hi[J].x, LOG2E, bias2));           \
        float q3 = exp2fast(__builtin_fmaf(hi[J].y, LOG2E, bias3));           \
        float s65 = a6 + a5, s43 = a4 + a3, s21 = a2 + a1;                    \
        float na7 = (a7 + s65) * q3;                                          \
        float t7 = __shfl_up(na7, 1); /* consumed NEXT step as p7c */         \
        a6 = s65 * QB;                                                        \
        a5 = (a5 + s43) * q2;                                                 \
        a4 = s43 * QB;                                                        \
        a3 = (a3 + s21) * q1;                                                 \
        a2 = s21 * QB;                                                        \
        float s0p = a0 + p7c;                                                 \
        a1 = (a1 + s0p) * q0;                                                 \
        a0 = s0p * QB;                                                        \
        a7 = na7;                                                             \
        p7c = (lane == 0) ? 0.0f : t7;                                        \
    }

#define RENORM()                                                              \
    {                                                                         \
        float mx = fmaxf(fmaxf(fmaxf(a0, a1), fmaxf(a2, a3)),                 \
                         fmaxf(fmaxf(a4, a5), fmaxf(a6, a7)));                \
        mx = wave_red_max(mx); /* alphas >= 0, mx > 0 always */               \
        int e_ = (int)((__float_as_uint(mx) >> 23) & 255) - 127;              \
        float scale_ = __uint_as_float((unsigned)(127 - e_) << 23);           \
        a0 *= scale_; a1 *= scale_; a2 *= scale_; a3 *= scale_;               \
        a4 *= scale_; a5 *= scale_; a6 *= scale_; a7 *= scale_;               \
        p7c *= scale_; /* carried pre-renorm snapshot must be rescaled */     \
        Esum += (float)e_;                                                    \
    }

__global__ void __launch_bounds__(64, 1) ctc_kernel(const float* __restrict__ attn,
                                                    const int* __restrict__ text_lens,
                                                    const int* __restrict__ mel_lens,
                                                    const float* __restrict__ Z2,
                                                    float* __restrict__ out) {
    int b = blockIdx.x;
    int lane = threadIdx.x;
    int L = text_lens[b];
    int n_t = mel_lens[b];
    const char* pbase = (const char*)(attn + (size_t)b * Tn * Un);

    // per-lane safe byte offsets within a 1000B row (8B aligned, never OOB):
    // lane62 hi aliases lo (its cols 250/251 are always masked since L<=250),
    // lane63 reads col 0 (all its states masked).
    int voff_lo = lane * 16, voff_hi = lane * 16 + 8;
    if (lane == 62) { voff_lo = 992; voff_hi = 992; }
    if (lane == 63) { voff_lo = 0;   voff_hi = 0;   }
    int c0 = lane * 4;
    float bias0 = (c0 + 0 < L) ? 0.0f : -1000000.0f;
    float bias1 = (c0 + 1 < L) ? 0.0f : -1000000.0f;
    float bias2 = (c0 + 2 < L) ? 0.0f : -1000000.0f;
    float bias3 = (c0 + 3 < L) ? 0.0f : -1000000.0f;

    const float QB = 0.36787944117144233f;  // e^-1 (blank, unnormalized)
    float a0 = (lane == 0) ? 1.0f : 0.0f;
    float a1 = 0.0f, a2 = 0.0f, a3 = 0.0f, a4 = 0.0f, a5 = 0.0f, a6 = 0.0f, a7 = 0.0f;
    float p7c = 0.0f;   // carried shfl_up(a7): initial alphas are 0 -> 0
    float Esum = 0.0f;  // accumulated renorm exponent, log2 units

    v2f lo[16], hi[16];
    int last = n_t - 1;

    // prologue: 16 rows = 32 loads in flight
#pragma unroll
    for (int j = 0; j < 16; ++j) CTC_REFILL(j, j);

    int full = n_t & ~15;
    int t = 0;
    for (; t < full; t += 16) {
        CTC_STEP(0, 30);  CTC_REFILL(0, t + 16);
        CTC_STEP(1, 30);  CTC_REFILL(1, t + 17);
        CTC_STEP(2, 30);  CTC_REFILL(2, t + 18);
        CTC_STEP(3, 30);  CTC_REFILL(3, t + 19);
        CTC_STEP(4, 30);  CTC_REFILL(4, t + 20);
        CTC_STEP(5, 30);  CTC_REFILL(5, t + 21);
        CTC_STEP(6, 30);  CTC_REFILL(6, t + 22);
        CTC_STEP(7, 30);  CTC_REFILL(7, t + 23);
        RENORM();
        CTC_STEP(8, 30);  CTC_REFILL(8, t + 24);
        CTC_STEP(9, 30);  CTC_REFILL(9, t + 25);
        CTC_STEP(10, 30); CTC_REFILL(10, t + 26);
        CTC_STEP(11, 30); CTC_REFILL(11, t + 27);
        CTC_STEP(12, 30); CTC_REFILL(12, t + 28);
        CTC_STEP(13, 30); CTC_REFILL(13, t + 29);
        CTC_STEP(14, 30); CTC_REFILL(14, t + 30);
        CTC_STEP(15, 30); CTC_REFILL(15, t + 31);
        RENORM();
    }
    // tail (<= 15 steps); slots j hold rows full+j from the last body refills
    // (or the prologue if n_t < 16). vmcnt(0): one-time full drain, then free.
    if (t + 0 < n_t) CTC_STEP(0, 0);
    if (t + 1 < n_t) CTC_STEP(1, 0);
    if (t + 2 < n_t) CTC_STEP(2, 0);
    if (t + 3 < n_t) CTC_STEP(3, 0);
    if (t + 4 < n_t) CTC_STEP(4, 0);
    if (t + 5 < n_t) CTC_STEP(5, 0);
    if (t + 6 < n_t) CTC_STEP(6, 0);
    if (t + 7 < n_t) CTC_STEP(7, 0);
    if (t + 8 < n_t) { RENORM(); CTC_STEP(8, 0); }  // cap unrenormed run at 8
    if (t + 9 < n_t) CTC_STEP(9, 0);
    if (t + 10 < n_t) CTC_STEP(10, 0);
    if (t + 11 < n_t) CTC_STEP(11, 0);
    if (t + 12 < n_t) CTC_STEP(12, 0);
    if (t + 13 < n_t) CTC_STEP(13, 0);
    if (t + 14 < n_t) CTC_STEP(14, 0);
    asm volatile("s_waitcnt vmcnt(0)" ::: "memory");  // drain stale prefetches

    __shared__ float sal[512];
    sal[lane * 8 + 0] = a0;
    sal[lane * 8 + 1] = a1;
    sal[lane * 8 + 2] = a2;
    sal[lane * 8 + 3] = a3;
    sal[lane * 8 + 4] = a4;
    sal[lane * 8 + 5] = a5;
    sal[lane * 8 + 6] = a6;
    sal[lane * 8 + 7] = a7;
    __syncthreads();

    // sum of log-softmax denominators over t < n_t (log2 units)
    float zs = 0.0f;
    for (int i = lane; i < n_t; i += 64) zs += Z2[b * Tn + i];
    zs = wave_red_sum(zs);

    if (lane == 0) {
        float ssum = sal[2 * L] + sal[2 * L - 1];
        float fin = (log2fast(ssum) + Esum - zs) * LN2;
        float loss = (ssum <= 0.0f) ? 0.0f : (-fin / (float)L);
        atomicAdd(out, loss * (1.0f / (float)Bn));
    }
}

extern "C" void kernel_launch(void* const* d_in, const int* in_sizes, int n_in,
                              void* d_out, int out_size, void* d_ws, size_t ws_size,
                              hipStream_t stream) {
    const float* attn = (const float*)d_in[0];
    const int* text_lens = (const int*)d_in[1];
    const int* mel_lens = (const int*)d_in[2];
    float* out = (float*)d_out;
    float* Z2 = (float*)d_ws;  // Bn*Tn floats = 256 KB

    (void)hipMemsetAsync(d_out, 0, sizeof(float), stream);
    zrow_kernel<<<(Bn * Tn + 3) / 4, 256, 0, stream>>>(attn, text_lens, Z2);
    ctc_kernel<<<Bn, 64, 0, stream>>>(attn, text_lens, mel_lens, Z2, out);
}

// Round 7
// 172.471 us; speedup vs baseline: 4.9293x; 1.1253x over previous
//
#include <hip/hip_runtime.h>

#define NEGF -1000000000.0f
#define LOG2E 1.4426950408889634f
#define LN2 0.6931471805599453f

constexpr int Bn = 64;
constexpr int Tn = 1000;
constexpr int Un = 250;

// gfx950-native base-2 transcendentals: v_exp_f32 is 2^x, v_log_f32 is log2(x)
__device__ __forceinline__ float exp2fast(float x) { return __builtin_amdgcn_exp2f(x); }
__device__ __forceinline__ float log2fast(float x) { return __builtin_amdgcn_logf(x); }

// ---------------------------------------------------------------------------
// DPP cross-lane ops (gfx9-lineage controls, retained on CDNA4; 0x142/0x143
// validated on-device in round 6).
//   wave_shr:1 (0x138) + bound_ctrl=1: lane i <- lane i-1, lane 0 <- 0.
//   Reductions: row_shr 1/2/4/8 + row_bcast:15/31, result in lane 63.
// ---------------------------------------------------------------------------
template <int CTRL>
__device__ __forceinline__ float dppmov(float x) {
    return __int_as_float(__builtin_amdgcn_update_dpp(
        0, __float_as_int(x), CTRL, 0xf, 0xf, true));
}
__device__ __forceinline__ float dpp_wave_shr1(float x) { return dppmov<0x138>(x); }

__device__ __forceinline__ float wave_red_max(float x) {  // = max(max_x, 0)
    x = fmaxf(x, dppmov<0x111>(x));
    x = fmaxf(x, dppmov<0x112>(x));
    x = fmaxf(x, dppmov<0x114>(x));
    x = fmaxf(x, dppmov<0x118>(x));
    x = fmaxf(x, dppmov<0x142>(x));
    x = fmaxf(x, dppmov<0x143>(x));
    return __int_as_float(__builtin_amdgcn_readlane(__float_as_int(x), 63));
}
__device__ __forceinline__ float wave_red_sum(float x) {
    x += dppmov<0x111>(x);
    x += dppmov<0x112>(x);
    x += dppmov<0x114>(x);
    x += dppmov<0x118>(x);
    x += dppmov<0x142>(x);
    x += dppmov<0x143>(x);
    return __int_as_float(__builtin_amdgcn_readlane(__float_as_int(x), 63));
}

// ---------------------------------------------------------------------------
// Kernel 1: per-row log-softmax denominator, in log2 units.
// Z2[row] = log2( 2^(-LOG2E) + sum_{u<L} 2^(attn[row,u]*LOG2E) )
// 4 rows per wave, 4 waves per block -> 1000 workgroups (16x fewer dispatches
// than one-row-per-wave; each tiny-work wg costs dispatch overhead).
// All 16 loads issue up front (independent); 4 reduction chains interleave.
// Also zeroes d_out (runs before ctc_kernel on the same stream).
// ---------------------------------------------------------------------------
__global__ void __launch_bounds__(256) zrow_kernel(const float* __restrict__ attn,
                                                   const int* __restrict__ text_lens,
                                                   float* __restrict__ Z2,
                                                   float* __restrict__ out) {
    if (blockIdx.x == 0 && threadIdx.x == 0) *out = 0.0f;
    int wid = threadIdx.x >> 6;
    int lane = threadIdx.x & 63;
    int row0 = (blockIdx.x * 4 + wid) * 4;     // 4 consecutive rows per wave

    float v[4][4];
    int Ls[4];
#pragma unroll
    for (int r = 0; r < 4; ++r) {
        int row = row0 + r;
        Ls[r] = text_lens[row / Tn];
        const float* p = attn + (size_t)row * Un;
#pragma unroll
        for (int i = 0; i < 4; ++i) {
            int u = lane + 64 * i;
            v[r][i] = (u < Un) ? p[u] : 0.0f;  // in-bounds read; mask vs L below
        }
    }
#pragma unroll
    for (int r = 0; r < 4; ++r) {
        int L = Ls[r];
        float m = (lane == 0) ? -LOG2E : NEGF;
#pragma unroll
        for (int i = 0; i < 4; ++i) {
            int u = lane + 64 * i;
            v[r][i] = (u < L) ? v[r][i] * LOG2E : NEGF;
            m = fmaxf(m, v[r][i]);
        }
        m = wave_red_max(m);                   // wave-uniform; = max(max, 0), exact shift
        float s = (lane == 0) ? exp2fast(-LOG2E - m) : 0.0f;
#pragma unroll
        for (int i = 0; i < 4; ++i) s += exp2fast(v[r][i] - m);  // NEGF-m -> 0
        s = wave_red_sum(s);
        if (lane == 0) Z2[row0 + r] = m + log2fast(s);
    }
}

// ---------------------------------------------------------------------------
// Kernel 2: CTC forward recursion in the LINEAR domain, one wave per batch.
// State s = lane*8 + j. Every 8 steps: wave-uniform power-of-2 renorm (DPP
// max + exponent bits), Esum accumulates the stripped exponent (log2 units).
//   odd  s: a' = (a[s]+a[s-1]+a[s-2]) * e^{logit[col]}
//   even s: a' = (a[s]+a[s-1]) * e^{-1}
// Column masking folded into the exp2 input as an fma bias (-1e6 -> q=0), so
// garbage states (s > 2L) stay exactly 0.
// Cross-lane alpha[8*lane-1]: DPP wave_shr:1 on old a7 (bound_ctrl=1 zeroes
// lane 0) — one VALU op, replaces the ~120-cyc ds_bpermute of round 6.
// Loads: 16-row-deep rotation of inline-asm global_load_dwordx2 with SGPR row
// base + constant per-lane voffset, s_waitcnt vmcnt(30) before consuming a
// slot. Branchless 16-step body; guarded 15-step tail.
// ---------------------------------------------------------------------------
typedef float v2f __attribute__((ext_vector_type(2)));

#define CTC_REFILL(J, T)                                                      \
    {                                                                         \
        int tl_ = (T) <= last ? (T) : last;                                   \
        const char* rowp_ = pbase + (size_t)tl_ * 1000;                       \
        asm volatile("global_load_dwordx2 %0, %1, %2"                         \
                     : "=v"(lo[J]) : "v"(voff_lo), "s"(rowp_));               \
        asm volatile("global_load_dwordx2 %0, %1, %2"                         \
                     : "=v"(hi[J]) : "v"(voff_hi), "s"(rowp_));               \
    }

#define CTC_STEP(J, WCNT)                                                     \
    {                                                                         \
        asm volatile("s_waitcnt vmcnt(" #WCNT ")"                             \
                     : "+v"(lo[J]), "+v"(hi[J]));                             \
        float q0 = exp2fast(__builtin_fmaf(lo[J].x, LOG2E, bias0));           \
        float q1 = exp2fast(__builtin_fmaf(lo[J].y, LOG2E, bias1));           \
        float q2 = exp2fast(__builtin_fmaf(hi[J].x, LOG2E, bias2));           \
        float q3 = exp2fast(__builtin_fmaf(hi[J].y, LOG2E, bias3));           \
        float p7 = dpp_wave_shr1(a7); /* old a7 of lane-1; lane0 -> 0 */      \
        float s65 = a6 + a5, s43 = a4 + a3, s21 = a2 + a1, s0p = a0 + p7;     \
        a7 = (a7 + s65) * q3;  a6 = s65 * QB;                                 \
        a5 = (a5 + s43) * q2;  a4 = s43 * QB;                                 \
        a3 = (a3 + s21) * q1;  a2 = s21 * QB;                                 \
        a1 = (a1 + s0p) * q0;  a0 = s0p * QB;                                 \
    }

#define RENORM()                                                              \
    {                                                                         \
        float mx = fmaxf(fmaxf(fmaxf(a0, a1), fmaxf(a2, a3)),                 \
                         fmaxf(fmaxf(a4, a5), fmaxf(a6, a7)));                \
        mx = wave_red_max(mx); /* alphas >= 0, mx > 0 always */               \
        int e_ = (int)((__float_as_uint(mx) >> 23) & 255) - 127;              \
        float scale_ = __uint_as_float((unsigned)(127 - e_) << 23);           \
        a0 *= scale_; a1 *= scale_; a2 *= scale_; a3 *= scale_;               \
        a4 *= scale_; a5 *= scale_; a6 *= scale_; a7 *= scale_;               \
        Esum += (float)e_;                                                    \
    }

__global__ void __launch_bounds__(64, 1) ctc_kernel(const float* __restrict__ attn,
                                                    const int* __restrict__ text_lens,
                                                    const int* __restrict__ mel_lens,
                                                    const float* __restrict__ Z2,
                                                    float* __restrict__ out) {
    int b = blockIdx.x;
    int lane = threadIdx.x;
    int L = text_lens[b];
    int n_t = mel_lens[b];
    const char* pbase = (const char*)(attn + (size_t)b * Tn * Un);

    // per-lane safe byte offsets within a 1000B row (8B aligned, never OOB):
    // lane62 hi aliases lo (its cols 250/251 are always masked since L<=250),
    // lane63 reads col 0 (all its states masked).
    int voff_lo = lane * 16, voff_hi = lane * 16 + 8;
    if (lane == 62) { voff_lo = 992; voff_hi = 992; }
    if (lane == 63) { voff_lo = 0;   voff_hi = 0;   }
    int c0 = lane * 4;
    float bias0 = (c0 + 0 < L) ? 0.0f : -1000000.0f;
    float bias1 = (c0 + 1 < L) ? 0.0f : -1000000.0f;
    float bias2 = (c0 + 2 < L) ? 0.0f : -1000000.0f;
    float bias3 = (c0 + 3 < L) ? 0.0f : -1000000.0f;

    const float QB = 0.36787944117144233f;  // e^-1 (blank, unnormalized)
    float a0 = (lane == 0) ? 1.0f : 0.0f;
    float a1 = 0.0f, a2 = 0.0f, a3 = 0.0f, a4 = 0.0f, a5 = 0.0f, a6 = 0.0f, a7 = 0.0f;
    float Esum = 0.0f;  // accumulated renorm exponent, log2 units

    v2f lo[16], hi[16];
    int last = n_t - 1;

    // prologue: 16 rows = 32 loads in flight
#pragma unroll
    for (int j = 0; j < 16; ++j) CTC_REFILL(j, j);

    int full = n_t & ~15;
    int t = 0;
    for (; t < full; t += 16) {
        CTC_STEP(0, 30);  CTC_REFILL(0, t + 16);
        CTC_STEP(1, 30);  CTC_REFILL(1, t + 17);
        CTC_STEP(2, 30);  CTC_REFILL(2, t + 18);
        CTC_STEP(3, 30);  CTC_REFILL(3, t + 19);
        CTC_STEP(4, 30);  CTC_REFILL(4, t + 20);
        CTC_STEP(5, 30);  CTC_REFILL(5, t + 21);
        CTC_STEP(6, 30);  CTC_REFILL(6, t + 22);
        CTC_STEP(7, 30);  CTC_REFILL(7, t + 23);
        RENORM();
        CTC_STEP(8, 30);  CTC_REFILL(8, t + 24);
        CTC_STEP(9, 30);  CTC_REFILL(9, t + 25);
        CTC_STEP(10, 30); CTC_REFILL(10, t + 26);
        CTC_STEP(11, 30); CTC_REFILL(11, t + 27);
        CTC_STEP(12, 30); CTC_REFILL(12, t + 28);
        CTC_STEP(13, 30); CTC_REFILL(13, t + 29);
        CTC_STEP(14, 30); CTC_REFILL(14, t + 30);
        CTC_STEP(15, 30); CTC_REFILL(15, t + 31);
        RENORM();
    }
    // tail (<= 15 steps); slots j hold rows full+j from the last body refills
    // (or the prologue if n_t < 16). vmcnt(0): one-time full drain, then free.
    if (t + 0 < n_t) CTC_STEP(0, 0);
    if (t + 1 < n_t) CTC_STEP(1, 0);
    if (t + 2 < n_t) CTC_STEP(2, 0);
    if (t + 3 < n_t) CTC_STEP(3, 0);
    if (t + 4 < n_t) CTC_STEP(4, 0);
    if (t + 5 < n_t) CTC_STEP(5, 0);
    if (t + 6 < n_t) CTC_STEP(6, 0);
    if (t + 7 < n_t) CTC_STEP(7, 0);
    if (t + 8 < n_t) { RENORM(); CTC_STEP(8, 0); }  // cap unrenormed run at 8
    if (t + 9 < n_t) CTC_STEP(9, 0);
    if (t + 10 < n_t) CTC_STEP(10, 0);
    if (t + 11 < n_t) CTC_STEP(11, 0);
    if (t + 12 < n_t) CTC_STEP(12, 0);
    if (t + 13 < n_t) CTC_STEP(13, 0);
    if (t + 14 < n_t) CTC_STEP(14, 0);
    asm volatile("s_waitcnt vmcnt(0)" ::: "memory");  // drain stale prefetches

    __shared__ float sal[512];
    sal[lane * 8 + 0] = a0;
    sal[lane * 8 + 1] = a1;
    sal[lane * 8 + 2] = a2;
    sal[lane * 8 + 3] = a3;
    sal[lane * 8 + 4] = a4;
    sal[lane * 8 + 5] = a5;
    sal[lane * 8 + 6] = a6;
    sal[lane * 8 + 7] = a7;
    __syncthreads();

    // sum of log-softmax denominators over t < n_t (log2 units)
    float zs = 0.0f;
    for (int i = lane; i < n_t; i += 64) zs += Z2[b * Tn + i];
    zs = wave_red_sum(zs);

    if (lane == 0) {
        float ssum = sal[2 * L] + sal[2 * L - 1];
        float fin = (log2fast(ssum) + Esum - zs) * LN2;
        float loss = (ssum <= 0.0f) ? 0.0f : (-fin / (float)L);
        atomicAdd(out, loss * (1.0f / (float)Bn));
    }
}

extern "C" void kernel_launch(void* const* d_in, const int* in_sizes, int n_in,
                              void* d_out, int out_size, void* d_ws, size_t ws_size,
                              hipStream_t stream) {
    const float* attn = (const float*)d_in[0];
    const int* text_lens = (const int*)d_in[1];
    const int* mel_lens = (const int*)d_in[2];
    float* out = (float*)d_out;
    float* Z2 = (float*)d_ws;  // Bn*Tn floats = 256 KB

    // zrow also zeroes d_out (stream-ordered before ctc_kernel's atomicAdd)
    zrow_kernel<<<Bn * Tn / 16, 256, 0, stream>>>(attn, text_lens, Z2, out);
    ctc_kernel<<<Bn, 64, 0, stream>>>(attn, text_lens, mel_lens, Z2, out);
}